// Round 7
// baseline (1239.580 us; speedup 1.0000x reference)
//
#include <hip/hip_runtime.h>

#define NQ 32768
#define NP 8192
#define FD 32
#define KNN 8

#define GRID 32
#define NCELL (GRID*GRID*GRID)
#define HCELL 0.375f
#define GLO  -6.0f
#define INVH 2.66666675f
#define QPB 64
#define TBM 256

// ws layout (assumes ws_size >= 819200 bytes):
// pcnt[NCELL] | poff[NCELL] | qcnt[NCELL] | qoff[NCELL] | packed[NP]f4 | pidx[NP] | qids[NQ]

__device__ __forceinline__ int cellco(float x) {
    int c = (int)floorf((x - GLO) * INVH);
    return min(GRID - 1, max(0, c));
}
__device__ __forceinline__ unsigned morton15(int x, int y, int z) {
    unsigned m = 0;
#pragma unroll
    for (int b = 0; b < 5; ++b)
        m |= (((unsigned)(x >> b) & 1u) << (3 * b)) | (((unsigned)(y >> b) & 1u) << (3 * b + 1))
           | (((unsigned)(z >> b) & 1u) << (3 * b + 2));
    return m;
}

__global__ void k_hist(const float* __restrict__ xyz, const float* __restrict__ points,
                       unsigned* __restrict__ pcnt, unsigned* __restrict__ qcnt) {
    int t = blockIdx.x * blockDim.x + threadIdx.x;
    if (t < NP) {
        int cx = cellco(points[t*3]), cy = cellco(points[t*3+1]), cz = cellco(points[t*3+2]);
        atomicAdd(&pcnt[cx + GRID*cy + GRID*GRID*cz], 1u);
    }
    if (t < NQ) {
        int cx = cellco(xyz[t*3]), cy = cellco(xyz[t*3+1]), cz = cellco(xyz[t*3+2]);
        atomicAdd(&qcnt[morton15(cx, cy, cz)], 1u);
    }
}

// single-block exclusive scan of both cell-count arrays; writes start into B and
// start-cursor into A (scatter advances A to end; main uses B=start, A=end).
__global__ __launch_bounds__(1024) void k_scan(unsigned* __restrict__ pcnt, unsigned* __restrict__ poff,
                                               unsigned* __restrict__ qcnt, unsigned* __restrict__ qoff) {
    __shared__ unsigned wsum[16];
    const int t = threadIdx.x, lane = t & 63, w = t >> 6;
    for (int phase = 0; phase < 2; ++phase) {
        unsigned* A = phase ? qcnt : pcnt;
        unsigned* B = phase ? qoff : poff;
        unsigned loc[32]; unsigned s = 0;
#pragma unroll
        for (int j = 0; j < 32; ++j) { loc[j] = A[t*32 + j]; s += loc[j]; }
        unsigned v = s;
        for (int d = 1; d < 64; d <<= 1) { unsigned o = __shfl_up(v, d); if (lane >= d) v += o; }
        if (lane == 63) wsum[w] = v;
        __syncthreads();
        if (t < 16) {
            unsigned orig = wsum[t]; unsigned u = orig;
            for (int d = 1; d < 16; d <<= 1) { unsigned o = __shfl_up(u, d); if (t >= d) u += o; }
            wsum[t] = u - orig;                 // exclusive prefix of wave totals
        }
        __syncthreads();
        unsigned run = (v - s) + wsum[w];       // thread-exclusive base
#pragma unroll
        for (int j = 0; j < 32; ++j) { B[t*32 + j] = run; A[t*32 + j] = run; run += loc[j]; }
        __syncthreads();
    }
}

__global__ void k_scatter(const float* __restrict__ xyz, const float* __restrict__ points,
                          unsigned* __restrict__ pcur, unsigned* __restrict__ qcur,
                          float4* __restrict__ packed, unsigned* __restrict__ pidx,
                          unsigned* __restrict__ qids) {
#pragma clang fp contract(off)
    int t = blockIdx.x * blockDim.x + threadIdx.x;
    if (t < NP) {
        float px = points[t*3], py = points[t*3+1], pz = points[t*3+2];
        int c = cellco(px) + GRID*cellco(py) + GRID*GRID*cellco(pz);
        unsigned pos = atomicAdd(&pcur[c], 1u);
        float pn = (px*px + py*py) + pz*pz;     // np-exact: rounded squares, sequential add
        packed[pos] = make_float4(px, py, pz, pn);
        pidx[pos] = (unsigned)t;
    }
    if (t < NQ) {
        int cx = cellco(xyz[t*3]), cy = cellco(xyz[t*3+1]), cz = cellco(xyz[t*3+2]);
        unsigned qpos = atomicAdd(&qcur[morton15(cx, cy, cz)], 1u);
        qids[qpos] = (unsigned)t;
    }
}

__global__ __launch_bounds__(TBM) void k_main(const float* __restrict__ xyz,
        const float* __restrict__ points, const float* __restrict__ feats,
        const unsigned* __restrict__ poff, const unsigned* __restrict__ pend,
        const float4* __restrict__ packed, const unsigned* __restrict__ pidx,
        const unsigned* __restrict__ qids, float* __restrict__ out) {
#pragma clang fp contract(off)
    __shared__ unsigned long long smk[4][QPB][KNN];  // 16 KB partial lists
    __shared__ unsigned long long fin[QPB][KNN];     // 4 KB merged
    __shared__ unsigned sqid[QPB];
    __shared__ int sflag;

    const int t = threadIdx.x, lane = t & 63, w = t >> 6;
    const int b = blockIdx.x;

    const unsigned qid = qids[b * QPB + lane];
    if (t < QPB) sqid[t] = qids[b * QPB + t];
    const float qx = xyz[qid*3], qy = xyz[qid*3+1], qz = xyz[qid*3+2];
    const float qn = (qx*qx + qy*qy) + qz*qz;        // np-exact
    const int cx = cellco(qx), cy = cellco(qy), cz = cellco(qz);

    unsigned long long bk[KNN];
#pragma unroll
    for (int j = 0; j < KNN; ++j) bk[j] = ~0ull;
    bool qdone = false;

    for (int m = 0; ; ++m) {
        // ---- process shell m: cells at Chebyshev dist exactly m from each lane's home ----
        int cellct = 0;
        for (int dz = -m; dz <= m; ++dz)
        for (int dy = -m; dy <= m; ++dy)
        for (int dx = -m; dx <= m; ++dx) {
            int cd = max(abs(dx), max(abs(dy), abs(dz)));
            if (cd != m) continue;
            if (((cellct++) & 3) != w) continue;     // wave-split of shell cells (uniform)
            int ax = cx + dx, ay = cy + dy, az = cz + dz;
            bool ok = (ax >= 0) && (ax < GRID) && (ay >= 0) && (ay < GRID)
                   && (az >= 0) && (az < GRID) && !qdone;
            unsigned s = 0, len = 0;
            if (ok) {
                int cell = ax + GRID*ay + GRID*GRID*az;
                s = poff[cell];
                len = pend[cell] - s;
            }
            for (unsigned j = 0; ; ++j) {
                bool act = (j < len);
                if (!__any(act)) break;
                unsigned a = act ? (s + j) : 0u;
                float4 p = packed[a];
                unsigned oid = pidx[a];
                // np-exact d2: sgemm-style fma chain + (qn - 2dot) + pn  (bit-verified r3)
                float dot = __builtin_fmaf(qz, p.z, __builtin_fmaf(qy, p.y, qx * p.x));
                float d2  = (qn - 2.0f * dot) + p.w;
                unsigned bb = __float_as_uint(d2);
                unsigned mk = (bb & 0x80000000u) ? ~bb : (bb | 0x80000000u);
                unsigned long long key = ((unsigned long long)mk << 32) | oid;
                if (act && key < bk[KNN-1]) {
                    bool c0[KNN];
#pragma unroll
                    for (int k = 0; k < KNN; ++k) c0[k] = key < bk[k];
#pragma unroll
                    for (int k = KNN-1; k > 0; --k)
                        bk[k] = c0[k] ? (c0[k-1] ? bk[k-1] : key) : bk[k];
                    if (c0[0]) bk[0] = key;
                }
            }
        }
        __syncthreads();
#pragma unroll
        for (int j = 0; j < KNN; ++j) smk[w][lane][j] = bk[j];
        if (t == 0) sflag = 1;
        __syncthreads();
        // termination: merged d8 <= (m*h)^2 - margin  (all 4 partial d8s suffice)
        float mh = (float)m * HCELL;
        float bnd = mh * mh - 2e-3f;
        bool done = false;
        if (bnd > 0.0f) {
            unsigned bmk = __float_as_uint(bnd) | 0x80000000u;
            unsigned long long bkey = ((unsigned long long)bmk << 32) | 0xffffffffu;
            done = true;
#pragma unroll
            for (int ww = 0; ww < 4; ++ww) done = done && (smk[ww][lane][KNN-1] <= bkey);
        }
        qdone = done;
        if (!done) sflag = 0;                        // benign write race (same value)
        __syncthreads();
        if (sflag) break;
        if (m >= GRID - 1) break;                    // full grid covered -> exact
    }

    // ---- merge 4 sorted-8 partial lists per query (wave 0; r4-verified pattern) ----
    if (w == 0) {
        int h0 = 0, h1 = 0, h2 = 0, h3 = 0;
#pragma unroll
        for (int k = 0; k < KNN; ++k) {
            unsigned long long c0 = smk[0][lane][h0];
            unsigned long long c1 = smk[1][lane][h1];
            unsigned long long c2 = smk[2][lane][h2];
            unsigned long long c3 = smk[3][lane][h3];
            unsigned long long b01 = c0 <= c1 ? c0 : c1;
            unsigned long long b23 = c2 <= c3 ? c2 : c3;
            unsigned long long best = b01 <= b23 ? b01 : b23;
            fin[lane][k] = best;
            bool t0 = (best == c0);
            bool t1 = !t0 && (best == c1);
            bool t2 = !t0 && !t1 && (best == c2);
            bool t3 = !t0 && !t1 && !t2;
            h0 += t0; h1 += t1; h2 += t2; h3 += t3;
        }
    }
    __syncthreads();

    // ---- cooperative output (r5-verified layout), addressed by original qid ----
    const float4* feats4 = (const float4*)feats;
    float4* outf4 = (float4*)(out + (long)NQ * KNN * 3);
    for (int off = t; off < QPB * KNN * FD / 4; off += TBM) {
        int q = off >> 6; int r = off & 63; int j = r >> 3; int c4 = r & 7;
        unsigned nb = (unsigned)fin[q][j];
        unsigned oq = sqid[q];
        outf4[(long)oq * (KNN * FD / 4) + j * (FD / 4) + c4] = feats4[(long)nb * (FD / 4) + c4];
    }
    for (int off = t; off < QPB * KNN * 3; off += TBM) {
        int q = off / 24; int r = off - q * 24; int j = r / 3; int cc = r - j * 3;
        unsigned nb = (unsigned)fin[q][j];
        unsigned oq = sqid[q];
        out[(long)oq * (KNN * 3) + j * 3 + cc] = points[nb * 3 + cc];
    }
}

extern "C" void kernel_launch(void* const* d_in, const int* in_sizes, int n_in,
                              void* d_out, int out_size, void* d_ws, size_t ws_size,
                              hipStream_t stream) {
    const float* xyz    = (const float*)d_in[0];
    const float* points = (const float*)d_in[1];
    const float* feats  = (const float*)d_in[2];
    float* out = (float*)d_out;

    unsigned* pcnt = (unsigned*)d_ws;         // becomes end-cursor after scatter
    unsigned* poff = pcnt + NCELL;            // start offsets (preserved)
    unsigned* qcnt = poff + NCELL;
    unsigned* qoff = qcnt + NCELL;
    float4*   packed = (float4*)(qoff + NCELL);
    unsigned* pidx = (unsigned*)(packed + NP);
    unsigned* qids = pidx + NP;

    hipMemsetAsync(d_ws, 0, 4 * NCELL * sizeof(unsigned), stream);
    hipLaunchKernelGGL(k_hist,    dim3(NQ / 256), dim3(256), 0, stream, xyz, points, pcnt, qcnt);
    hipLaunchKernelGGL(k_scan,    dim3(1),        dim3(1024), 0, stream, pcnt, poff, qcnt, qoff);
    hipLaunchKernelGGL(k_scatter, dim3(NQ / 256), dim3(256), 0, stream, xyz, points, pcnt, qcnt,
                       packed, pidx, qids);
    hipLaunchKernelGGL(k_main,    dim3(NQ / QPB), dim3(TBM), 0, stream, xyz, points, feats,
                       poff, pcnt, packed, pidx, qids, out);
}

// Round 9
// 129.896 us; speedup vs baseline: 9.5429x; 9.5429x over previous
//
#include <hip/hip_runtime.h>

#define NQ 32768
#define NP 8192
#define FD 32
#define KNN 8
#define QW 8                 // queries per wave
#define WPB 4                // waves per block
#define TB 256
#define QBLK (QW * WPB)      // 32 queries per block
#define CHP 1024             // points per staged chunk
#define CAP 128              // candidate capacity per query (E~37, P(overflow)<1e-10)

typedef unsigned long long u64;

__device__ __forceinline__ u64 shfl_xor_u64(u64 k, int j) {
    unsigned lo = __shfl_xor((unsigned)k, j);
    unsigned hi = __shfl_xor((unsigned)(k >> 32), j);
    return ((u64)hi << 32) | lo;
}
// full 64-lane bitonic sort, ascending by lane (r5-verified pattern)
__device__ __forceinline__ u64 sort64_u64(u64 key, int lane) {
    for (int k2 = 2; k2 <= 64; k2 <<= 1)
        for (int j = k2 >> 1; j > 0; j >>= 1) {
            u64 o = shfl_xor_u64(key, j);
            bool keepMin = ((lane & k2) == 0) == ((lane & j) == 0);
            key = ((o < key) == keepMin) ? o : key;
        }
    return key;
}
// exact 8th-smallest of the 64 lane values (r6-verified f32 bitonic + readlane 7)
__device__ __forceinline__ float eighth_smallest64(float v, int lane) {
    for (int k2 = 2; k2 <= 64; k2 <<= 1)
        for (int j = k2 >> 1; j > 0; j >>= 1) {
            float o = __shfl_xor(v, j);
            bool keepMin = ((lane & k2) == 0) == ((lane & j) == 0);
            v = ((o < v) == keepMin) ? o : v;
        }
    return __uint_as_float((unsigned)__builtin_amdgcn_readlane((int)__float_as_uint(v), 7));
}

__global__ __launch_bounds__(TB) void knn_kernel(
    const float* __restrict__ xyz, const float* __restrict__ points,
    const float* __restrict__ feats, float* __restrict__ out)
{
#pragma clang fp contract(off)   // np-exact paths: explicit mul/add; fast paths: explicit fmaf
    __shared__ float4 sp[CHP];                    // 16 KB: (-2px,-2py,-2pz,pn)
    __shared__ unsigned short sidx16[QBLK * CAP]; // 8 KB candidate indices
    __shared__ int scnt[QBLK];

    const int t     = threadIdx.x;
    const int lane  = t & 63;
    const int wid   = t >> 6;
    const int qbase = blockIdx.x * QBLK + wid * QW;

    if (t < QBLK) scnt[t] = 0;

    float qx[QW], qy[QW], qz[QW], qn[QW], mn[QW], tscr[QW];
#pragma unroll
    for (int qq = 0; qq < QW; ++qq) {
        int q = qbase + qq;
        float a = xyz[q * 3 + 0], b = xyz[q * 3 + 1], c = xyz[q * 3 + 2];
        qx[qq] = a; qy[qq] = b; qz[qq] = c;
        qn[qq] = (a * a + b * b) + c * c;   // np-exact: rounded squares, sequential add
        mn[qq] = __builtin_inff();
        tscr[qq] = __builtin_inff();
    }

    // schedule: A = chunk 0 (min only), chunks 1-3 (min+screen), B = chunks 0,4,5,6,7 (screen)
    for (int step = 0; step < 9; ++step) {
        int c = (step <= 3) ? step : ((step == 4) ? 0 : step - 1);
        __syncthreads();
        for (int i = t; i < CHP; i += TB) {
            int pi = c * CHP + i;
            float px = points[pi * 3 + 0], py = points[pi * 3 + 1], pz = points[pi * 3 + 2];
            float pn = __builtin_fmaf(pz, pz, __builtin_fmaf(py, py, px * px)); // screen-only
            sp[i] = make_float4(-2.0f * px, -2.0f * py, -2.0f * pz, pn);        // exact scales
        }
        __syncthreads();

        const bool doMin = (step < 4), doScr = (step != 0);
#pragma unroll 2
        for (int s = 0; s < CHP / 64; ++s) {
            float4 p = sp[s * 64 + lane];
            int gidx = c * CHP + s * 64 + lane;
#pragma unroll
            for (int qq = 0; qq < QW; ++qq) {
                // g = pn - 2*dot in 3 fma (screen space; margin covers g-vs-np-d2 gap)
                float g = __builtin_fmaf(qx[qq], p.x,
                          __builtin_fmaf(qy[qq], p.y,
                          __builtin_fmaf(qz[qq], p.z, p.w)));
                if (doMin) mn[qq] = fminf(mn[qq], g);
                if (doScr) {
                    if (__builtin_expect(g <= tscr[qq], 0)) {
                        int wq = wid * QW + qq;
                        int slot = atomicAdd(&scnt[wq], 1);
                        if (slot < CAP) sidx16[wq * CAP + slot] = (unsigned short)gidx;
                    }
                }
            }
        }

        if (step == 0 || step == 3) {
            // tight valid bound: 8th-smallest of 64 lane-mins (each an actual g of a
            // distinct point => sub-multiset order statistic >= full-set 8th smallest)
#pragma unroll
            for (int qq = 0; qq < QW; ++qq)
                tscr[qq] = eighth_smallest64(mn[qq], lane) + 1e-3f;
        }
    }
    // no cross-wave data from here: each wave owns its queries' candidates

    // ---- Phase C: np-exact d2 recompute, u64 sort(s), top-8, output ----
    const float4* feats4 = (const float4*)feats;
    float4* outf4 = (float4*)(out + (long)NQ * KNN * 3);
#pragma unroll 1
    for (int qq = 0; qq < QW; ++qq) {
        int wq = wid * QW + qq;
        int cnt = scnt[wq]; if (cnt > CAP) cnt = CAP;

        u64 key1 = ~0ull;
        if (lane < cnt) {
            int idx = sidx16[wq * CAP + lane];
            float px = points[idx * 3 + 0], py = points[idx * 3 + 1], pz = points[idx * 3 + 2];
            float pn  = (px * px + py * py) + pz * pz;                 // np-exact
            float dot = __builtin_fmaf(qz[qq], pz, __builtin_fmaf(qy[qq], py, qx[qq] * px));
            float d2  = (qn[qq] - 2.0f * dot) + pn;
            unsigned b = __float_as_uint(d2);
            unsigned mk = (b & 0x80000000u) ? ~b : (b | 0x80000000u);  // monotone map
            key1 = ((u64)mk << 32) | (unsigned)idx;                    // (value, stable idx)
        }
        u64 v = sort64_u64(key1, lane);

        if (cnt > 64) {                       // wave-uniform, rare (P(cnt>64) ~ 1e-5)
            u64 key2 = ~0ull;
            if (lane + 64 < cnt) {
                int idx = sidx16[wq * CAP + 64 + lane];
                float px = points[idx * 3 + 0], py = points[idx * 3 + 1], pz = points[idx * 3 + 2];
                float pn  = (px * px + py * py) + pz * pz;
                float dot = __builtin_fmaf(qz[qq], pz, __builtin_fmaf(qy[qq], py, qx[qq] * px));
                float d2  = (qn[qq] - 2.0f * dot) + pn;
                unsigned b = __float_as_uint(d2);
                unsigned mk = (b & 0x80000000u) ? ~b : (b | 0x80000000u);
                key2 = ((u64)mk << 32) | (unsigned)idx;
            }
            u64 s2 = sort64_u64(key2, lane);
            // lanes 8..15 take s2[15-lane] (descending) -> lanes 0..15 bitonic; 4-step merge
            int src = (15 - lane) & 63;
            unsigned lo2 = __shfl((unsigned)s2, src);
            unsigned hi2 = __shfl((unsigned)(s2 >> 32), src);
            u64 kr = ((u64)hi2 << 32) | lo2;
            u64 m = (lane < 8) ? v : ((lane < 16) ? kr : ~0ull);
#pragma unroll
            for (int j = 8; j > 0; j >>= 1) {
                u64 o = shfl_xor_u64(m, j);
                bool low = (lane & j) == 0;
                m = low ? (o < m ? o : m) : (o < m ? m : o);
            }
            v = m;
        }

        // lanes 0..7 hold top-8 ascending (r5/r6-verified output layout)
        int q = qbase + qq;
        int nb = __shfl((int)(unsigned)v, lane >> 3);
        outf4[(long)q * (KNN * FD / 4) + lane] = feats4[(long)nb * (FD / 4) + (lane & 7)];
        int j2 = lane / 3;
        int nb2 = __shfl((int)(unsigned)v, j2);
        if (lane < 24) {
            out[(long)q * (KNN * 3) + lane] = points[nb2 * 3 + (lane - j2 * 3)];
        }
    }
}

extern "C" void kernel_launch(void* const* d_in, const int* in_sizes, int n_in,
                              void* d_out, int out_size, void* d_ws, size_t ws_size,
                              hipStream_t stream) {
    const float* xyz    = (const float*)d_in[0];
    const float* points = (const float*)d_in[1];
    const float* feats  = (const float*)d_in[2];
    float* out = (float*)d_out;
    hipLaunchKernelGGL(knn_kernel, dim3(NQ / QBLK), dim3(TB), 0, stream,
                       xyz, points, feats, out);
}

// Round 10
// 100.016 us; speedup vs baseline: 12.3938x; 1.2987x over previous
//
#include <hip/hip_runtime.h>

#define NQ 32768
#define NP 8192
#define FD 32
#define KNN 8
#define QW 4                 // queries per wave
#define WPB 8                // waves per block
#define TB 512
#define QBLK (QW * WPB)      // 32 queries per block
#define CHP 1024             // points per staged chunk
#define CAP 128              // candidate capacity per query (r9-validated)

typedef unsigned long long u64;

__device__ __forceinline__ u64 shfl_xor_u64(u64 k, int j) {
    unsigned lo = __shfl_xor((unsigned)k, j);
    unsigned hi = __shfl_xor((unsigned)(k >> 32), j);
    return ((u64)hi << 32) | lo;
}
// full 64-lane bitonic sort, ascending by lane (r5-verified pattern)
__device__ __forceinline__ u64 sort64_u64(u64 key, int lane) {
    for (int k2 = 2; k2 <= 64; k2 <<= 1)
        for (int j = k2 >> 1; j > 0; j >>= 1) {
            u64 o = shfl_xor_u64(key, j);
            bool keepMin = ((lane & k2) == 0) == ((lane & j) == 0);
            key = ((o < key) == keepMin) ? o : key;
        }
    return key;
}
// exact 8th-smallest of the 64 lane values (r6-verified f32 bitonic + readlane 7)
__device__ __forceinline__ float eighth_smallest64(float v, int lane) {
    for (int k2 = 2; k2 <= 64; k2 <<= 1)
        for (int j = k2 >> 1; j > 0; j >>= 1) {
            float o = __shfl_xor(v, j);
            bool keepMin = ((lane & k2) == 0) == ((lane & j) == 0);
            v = ((o < v) == keepMin) ? o : v;
        }
    return __uint_as_float((unsigned)__builtin_amdgcn_readlane((int)__float_as_uint(v), 7));
}

__global__ __launch_bounds__(TB) void knn_kernel(
    const float* __restrict__ xyz, const float* __restrict__ points,
    const float* __restrict__ feats, float* __restrict__ out)
{
#pragma clang fp contract(off)   // np-exact paths: explicit mul/add; fast paths: explicit fmaf
    __shared__ float4 sp[CHP];                    // 16 KB: (-2px,-2py,-2pz,pn)
    __shared__ unsigned short sidx16[QBLK * CAP]; // 8 KB candidate indices
    __shared__ int scnt[QBLK];

    const int t     = threadIdx.x;
    const int lane  = t & 63;
    const int wid   = t >> 6;
    const int qbase = blockIdx.x * QBLK + wid * QW;

    if (t < QBLK) scnt[t] = 0;

    float qx[QW], qy[QW], qz[QW], qn[QW], mn[QW], tscr[QW];
#pragma unroll
    for (int qq = 0; qq < QW; ++qq) {
        int q = qbase + qq;
        float a = xyz[q * 3 + 0], b = xyz[q * 3 + 1], c = xyz[q * 3 + 2];
        qx[qq] = a; qy[qq] = b; qz[qq] = c;
        qn[qq] = (a * a + b * b) + c * c;   // np-exact: rounded squares, sequential add
        mn[qq] = __builtin_inff();
        tscr[qq] = __builtin_inff();
    }

    // schedule (r9-validated): A = chunk 0 (min only), chunks 1-3 (min+screen),
    //                          B = chunks 0,4,5,6,7 (screen only)
    for (int step = 0; step < 9; ++step) {
        int c = (step <= 3) ? step : ((step == 4) ? 0 : step - 1);
        __syncthreads();
        for (int i = t; i < CHP; i += TB) {
            int pi = c * CHP + i;
            float px = points[pi * 3 + 0], py = points[pi * 3 + 1], pz = points[pi * 3 + 2];
            float pn = __builtin_fmaf(pz, pz, __builtin_fmaf(py, py, px * px)); // screen-only
            sp[i] = make_float4(-2.0f * px, -2.0f * py, -2.0f * pz, pn);        // exact scales
        }
        __syncthreads();

        const bool doMin = (step < 4), doScr = (step != 0);
#pragma unroll 2
        for (int s = 0; s < CHP / 64; ++s) {
            float4 p = sp[s * 64 + lane];
            int gidx = c * CHP + s * 64 + lane;
#pragma unroll
            for (int qq = 0; qq < QW; ++qq) {
                // g = pn - 2*dot in 3 fma (screen space; margin covers g-vs-np-d2 gap)
                float g = __builtin_fmaf(qx[qq], p.x,
                          __builtin_fmaf(qy[qq], p.y,
                          __builtin_fmaf(qz[qq], p.z, p.w)));
                if (doMin) mn[qq] = fminf(mn[qq], g);
                if (doScr) {
                    if (__builtin_expect(g <= tscr[qq], 0)) {
                        int wq = wid * QW + qq;
                        int slot = atomicAdd(&scnt[wq], 1);
                        if (slot < CAP) sidx16[wq * CAP + slot] = (unsigned short)gidx;
                    }
                }
            }
        }

        if (step == 0 || step == 3) {
            // tight valid bound: 8th-smallest of 64 lane-mins (each an actual g of a
            // distinct point => sub-multiset order statistic >= full-set 8th smallest)
#pragma unroll
            for (int qq = 0; qq < QW; ++qq)
                tscr[qq] = eighth_smallest64(mn[qq], lane) + 1e-3f;
        }
    }
    // no cross-wave data from here: each wave owns its queries' candidates

    // ---- Phase C: np-exact d2 recompute, u64 sort(s), top-8, output ----
    const float4* feats4 = (const float4*)feats;
    float4* outf4 = (float4*)(out + (long)NQ * KNN * 3);
#pragma unroll 1
    for (int qq = 0; qq < QW; ++qq) {
        int wq = wid * QW + qq;
        int cnt = scnt[wq]; if (cnt > CAP) cnt = CAP;

        u64 key1 = ~0ull;
        if (lane < cnt) {
            int idx = sidx16[wq * CAP + lane];
            float px = points[idx * 3 + 0], py = points[idx * 3 + 1], pz = points[idx * 3 + 2];
            float pn  = (px * px + py * py) + pz * pz;                 // np-exact
            float dot = __builtin_fmaf(qz[qq], pz, __builtin_fmaf(qy[qq], py, qx[qq] * px));
            float d2  = (qn[qq] - 2.0f * dot) + pn;
            unsigned b = __float_as_uint(d2);
            unsigned mk = (b & 0x80000000u) ? ~b : (b | 0x80000000u);  // monotone map
            key1 = ((u64)mk << 32) | (unsigned)idx;                    // (value, stable idx)
        }
        u64 v = sort64_u64(key1, lane);

        if (cnt > 64) {                       // wave-uniform, rare
            u64 key2 = ~0ull;
            if (lane + 64 < cnt) {
                int idx = sidx16[wq * CAP + 64 + lane];
                float px = points[idx * 3 + 0], py = points[idx * 3 + 1], pz = points[idx * 3 + 2];
                float pn  = (px * px + py * py) + pz * pz;
                float dot = __builtin_fmaf(qz[qq], pz, __builtin_fmaf(qy[qq], py, qx[qq] * px));
                float d2  = (qn[qq] - 2.0f * dot) + pn;
                unsigned b = __float_as_uint(d2);
                unsigned mk = (b & 0x80000000u) ? ~b : (b | 0x80000000u);
                key2 = ((u64)mk << 32) | (unsigned)idx;
            }
            u64 s2 = sort64_u64(key2, lane);
            // lanes 8..15 take s2[15-lane] (descending) -> lanes 0..15 bitonic; 4-step merge
            int src = (15 - lane) & 63;
            unsigned lo2 = __shfl((unsigned)s2, src);
            unsigned hi2 = __shfl((unsigned)(s2 >> 32), src);
            u64 kr = ((u64)hi2 << 32) | lo2;
            u64 m = (lane < 8) ? v : ((lane < 16) ? kr : ~0ull);
#pragma unroll
            for (int j = 8; j > 0; j >>= 1) {
                u64 o = shfl_xor_u64(m, j);
                bool low = (lane & j) == 0;
                m = low ? (o < m ? o : m) : (o < m ? m : o);
            }
            v = m;
        }

        // lanes 0..7 hold top-8 ascending (r5/r6-verified output layout)
        int q = qbase + qq;
        int nb = __shfl((int)(unsigned)v, lane >> 3);
        outf4[(long)q * (KNN * FD / 4) + lane] = feats4[(long)nb * (FD / 4) + (lane & 7)];
        int j2 = lane / 3;
        int nb2 = __shfl((int)(unsigned)v, j2);
        if (lane < 24) {
            out[(long)q * (KNN * 3) + lane] = points[nb2 * 3 + (lane - j2 * 3)];
        }
    }
}

extern "C" void kernel_launch(void* const* d_in, const int* in_sizes, int n_in,
                              void* d_out, int out_size, void* d_ws, size_t ws_size,
                              hipStream_t stream) {
    const float* xyz    = (const float*)d_in[0];
    const float* points = (const float*)d_in[1];
    const float* feats  = (const float*)d_in[2];
    float* out = (float*)d_out;
    hipLaunchKernelGGL(knn_kernel, dim3(NQ / QBLK), dim3(TB), 0, stream,
                       xyz, points, feats, out);
}

// Round 11
// 78.114 us; speedup vs baseline: 15.8689x; 1.2804x over previous
//
#include <hip/hip_runtime.h>

#define NQ 32768
#define NP 8192
#define FD 32
#define KNN 8
#define QW 4                 // queries per wave
#define WPB 8                // waves per block
#define TB 512
#define QBLK (QW * WPB)      // 32 queries per block
#define CHP 1024             // points per staged chunk
#define CAP 128              // candidate capacity per query (r9-validated)

typedef unsigned long long u64;

__device__ __forceinline__ u64 shfl_xor_u64(u64 k, int j) {
    unsigned lo = __shfl_xor((unsigned)k, j);
    unsigned hi = __shfl_xor((unsigned)(k >> 32), j);
    return ((u64)hi << 32) | lo;
}
// full 64-lane bitonic sort, ascending by lane (r5-verified pattern)
__device__ __forceinline__ u64 sort64_u64(u64 key, int lane) {
    for (int k2 = 2; k2 <= 64; k2 <<= 1)
        for (int j = k2 >> 1; j > 0; j >>= 1) {
            u64 o = shfl_xor_u64(key, j);
            bool keepMin = ((lane & k2) == 0) == ((lane & j) == 0);
            key = ((o < key) == keepMin) ? o : key;
        }
    return key;
}
// exact 8th-smallest of the 64 lane values (r6-verified f32 bitonic + readlane 7)
__device__ __forceinline__ float eighth_smallest64(float v, int lane) {
    for (int k2 = 2; k2 <= 64; k2 <<= 1)
        for (int j = k2 >> 1; j > 0; j >>= 1) {
            float o = __shfl_xor(v, j);
            bool keepMin = ((lane & k2) == 0) == ((lane & j) == 0);
            v = ((o < v) == keepMin) ? o : v;
        }
    return __uint_as_float((unsigned)__builtin_amdgcn_readlane((int)__float_as_uint(v), 7));
}

__global__ __launch_bounds__(TB) void knn_kernel(
    const float* __restrict__ xyz, const float* __restrict__ points,
    const float* __restrict__ feats, float* __restrict__ out)
{
#pragma clang fp contract(off)   // np-exact paths: explicit mul/add; fast paths: explicit fmaf
    __shared__ float4 sp[CHP];                    // 16 KB: (-2px,-2py,-2pz,pn)
    __shared__ unsigned short sidx16[QBLK * CAP]; // 8 KB candidate indices
    __shared__ int scnt[QBLK];

    const int t     = threadIdx.x;
    const int lane  = t & 63;
    const int wid   = t >> 6;
    const int qbase = blockIdx.x * QBLK + wid * QW;

    if (t < QBLK) scnt[t] = 0;

    float qx[QW], qy[QW], qz[QW], qn[QW], mn[QW], tscr[QW];
#pragma unroll
    for (int qq = 0; qq < QW; ++qq) {
        int q = qbase + qq;
        float a = xyz[q * 3 + 0], b = xyz[q * 3 + 1], c = xyz[q * 3 + 2];
        qx[qq] = a; qy[qq] = b; qz[qq] = c;
        qn[qq] = (a * a + b * b) + c * c;   // np-exact: rounded squares, sequential add
        mn[qq] = __builtin_inff();
        tscr[qq] = __builtin_inff();
    }

    // schedule (r9-validated): step 0: chunk 0 min-only; steps 1-3: chunks 1-3 min+screen;
    //                          steps 4-8: chunks 0,4,5,6,7 screen-only
    for (int step = 0; step < 9; ++step) {
        int c = (step <= 3) ? step : ((step == 4) ? 0 : step - 1);
        __syncthreads();
        for (int i = t; i < CHP; i += TB) {
            int pi = c * CHP + i;
            float px = points[pi * 3 + 0], py = points[pi * 3 + 1], pz = points[pi * 3 + 2];
            float pn = __builtin_fmaf(pz, pz, __builtin_fmaf(py, py, px * px)); // screen-only
            sp[i] = make_float4(-2.0f * px, -2.0f * py, -2.0f * pz, pn);        // exact scales
        }
        __syncthreads();

        if (step == 0) {
            // ---- min-only loop: 3 fma + min per pair ----
#pragma unroll 2
            for (int s = 0; s < CHP / 64; ++s) {
                float4 p = sp[s * 64 + lane];
#pragma unroll
                for (int qq = 0; qq < QW; ++qq) {
                    float g = __builtin_fmaf(qx[qq], p.x,
                              __builtin_fmaf(qy[qq], p.y,
                              __builtin_fmaf(qz[qq], p.z, p.w)));
                    mn[qq] = fminf(mn[qq], g);
                }
            }
#pragma unroll
            for (int qq = 0; qq < QW; ++qq)
                tscr[qq] = eighth_smallest64(mn[qq], lane) + 1e-3f;
        } else if (step <= 3) {
            // ---- min+screen loop ----
#pragma unroll 2
            for (int s = 0; s < CHP / 64; ++s) {
                float4 p = sp[s * 64 + lane];
                int gidx = c * CHP + s * 64 + lane;
#pragma unroll
                for (int qq = 0; qq < QW; ++qq) {
                    float g = __builtin_fmaf(qx[qq], p.x,
                              __builtin_fmaf(qy[qq], p.y,
                              __builtin_fmaf(qz[qq], p.z, p.w)));
                    mn[qq] = fminf(mn[qq], g);
                    if (__builtin_expect(g <= tscr[qq], 0)) {
                        int wq = wid * QW + qq;
                        int slot = atomicAdd(&scnt[wq], 1);
                        if (slot < CAP) sidx16[wq * CAP + slot] = (unsigned short)gidx;
                    }
                }
            }
            if (step == 3) {
                // tight valid bound: 8th-smallest of 64 lane-mins over 4096 points
#pragma unroll
                for (int qq = 0; qq < QW; ++qq)
                    tscr[qq] = eighth_smallest64(mn[qq], lane) + 1e-3f;
            }
        } else {
            // ---- screen-only loop: 3 fma + cmp + rare branch ----
#pragma unroll 4
            for (int s = 0; s < CHP / 64; ++s) {
                float4 p = sp[s * 64 + lane];
                int gidx = c * CHP + s * 64 + lane;
#pragma unroll
                for (int qq = 0; qq < QW; ++qq) {
                    float g = __builtin_fmaf(qx[qq], p.x,
                              __builtin_fmaf(qy[qq], p.y,
                              __builtin_fmaf(qz[qq], p.z, p.w)));
                    if (__builtin_expect(g <= tscr[qq], 0)) {
                        int wq = wid * QW + qq;
                        int slot = atomicAdd(&scnt[wq], 1);
                        if (slot < CAP) sidx16[wq * CAP + slot] = (unsigned short)gidx;
                    }
                }
            }
        }
    }
    // no cross-wave data from here: each wave owns its queries' candidates

    // ---- Phase C: np-exact d2 recompute, u64 sort(s), top-8, output ----
    const float4* feats4 = (const float4*)feats;
    float4* outf4 = (float4*)(out + (long)NQ * KNN * 3);
#pragma unroll 1
    for (int qq = 0; qq < QW; ++qq) {
        int wq = wid * QW + qq;
        int cnt = scnt[wq]; if (cnt > CAP) cnt = CAP;

        u64 key1 = ~0ull;
        if (lane < cnt) {
            int idx = sidx16[wq * CAP + lane];
            float px = points[idx * 3 + 0], py = points[idx * 3 + 1], pz = points[idx * 3 + 2];
            float pn  = (px * px + py * py) + pz * pz;                 // np-exact
            float dot = __builtin_fmaf(qz[qq], pz, __builtin_fmaf(qy[qq], py, qx[qq] * px));
            float d2  = (qn[qq] - 2.0f * dot) + pn;
            unsigned b = __float_as_uint(d2);
            unsigned mk = (b & 0x80000000u) ? ~b : (b | 0x80000000u);  // monotone map
            key1 = ((u64)mk << 32) | (unsigned)idx;                    // (value, stable idx)
        }
        u64 v = sort64_u64(key1, lane);

        if (cnt > 64) {                       // wave-uniform, rare
            u64 key2 = ~0ull;
            if (lane + 64 < cnt) {
                int idx = sidx16[wq * CAP + 64 + lane];
                float px = points[idx * 3 + 0], py = points[idx * 3 + 1], pz = points[idx * 3 + 2];
                float pn  = (px * px + py * py) + pz * pz;
                float dot = __builtin_fmaf(qz[qq], pz, __builtin_fmaf(qy[qq], py, qx[qq] * px));
                float d2  = (qn[qq] - 2.0f * dot) + pn;
                unsigned b = __float_as_uint(d2);
                unsigned mk = (b & 0x80000000u) ? ~b : (b | 0x80000000u);
                key2 = ((u64)mk << 32) | (unsigned)idx;
            }
            u64 s2 = sort64_u64(key2, lane);
            // lanes 8..15 take s2[15-lane] (descending) -> lanes 0..15 bitonic; 4-step merge
            int src = (15 - lane) & 63;
            unsigned lo2 = __shfl((unsigned)s2, src);
            unsigned hi2 = __shfl((unsigned)(s2 >> 32), src);
            u64 kr = ((u64)hi2 << 32) | lo2;
            u64 m = (lane < 8) ? v : ((lane < 16) ? kr : ~0ull);
#pragma unroll
            for (int j = 8; j > 0; j >>= 1) {
                u64 o = shfl_xor_u64(m, j);
                bool low = (lane & j) == 0;
                m = low ? (o < m ? o : m) : (o < m ? m : o);
            }
            v = m;
        }

        // lanes 0..7 hold top-8 ascending (r5/r6-verified output layout)
        int q = qbase + qq;
        int nb = __shfl((int)(unsigned)v, lane >> 3);
        outf4[(long)q * (KNN * FD / 4) + lane] = feats4[(long)nb * (FD / 4) + (lane & 7)];
        int j2 = lane / 3;
        int nb2 = __shfl((int)(unsigned)v, j2);
        if (lane < 24) {
            out[(long)q * (KNN * 3) + lane] = points[nb2 * 3 + (lane - j2 * 3)];
        }
    }
}

extern "C" void kernel_launch(void* const* d_in, const int* in_sizes, int n_in,
                              void* d_out, int out_size, void* d_ws, size_t ws_size,
                              hipStream_t stream) {
    const float* xyz    = (const float*)d_in[0];
    const float* points = (const float*)d_in[1];
    const float* feats  = (const float*)d_in[2];
    float* out = (float*)d_out;
    hipLaunchKernelGGL(knn_kernel, dim3(NQ / QBLK), dim3(TB), 0, stream,
                       xyz, points, feats, out);
}